// Round 5
// baseline (6239.979 us; speedup 1.0000x reference)
//
#include <hip/hip_runtime.h>
#include <hip/hip_bf16.h>

typedef __attribute__((ext_vector_type(8))) short bf8;    // 8 bf16 (4 VGPRs)
typedef __attribute__((ext_vector_type(4))) float f32x4;  // MFMA accumulator
typedef __attribute__((ext_vector_type(4))) unsigned int u32x4;  // asm-safe 128-bit payload

#define T_SEQ 1024

__device__ __forceinline__ float sigm(float x) { return 1.f / (1.f + __expf(-x)); }
__device__ __forceinline__ float tanh_(float x) { return 2.f / (1.f + __expf(-2.f * x)) - 1.f; }

__device__ __forceinline__ short bf16s(float x) {
    union { __hip_bfloat16 h; short s; } u;
    u.h = __float2bfloat16(x);
    return u.s;
}

__device__ __forceinline__ bf8 pack_bf8(const float4 a, const float4 b) {
    bf8 r;
    r[0] = bf16s(a.x); r[1] = bf16s(a.y); r[2] = bf16s(a.z); r[3] = bf16s(a.w);
    r[4] = bf16s(b.x); r[5] = bf16s(b.y); r[6] = bf16s(b.z); r[7] = bf16s(b.w);
    return r;
}

// ---- sc1 (device-scope, LLC-coherent) access helpers -----------------------
// sc1 loads/stores bypass L1 and the non-device-coherent per-XCD L2, meeting at
// the Infinity Cache (instruction class proven cross-XCD-correct in rounds 3/4).
// Protocol round trips removed this round: no publish drain, no release, no
// acquire. Readiness is validated per-dword by a step tag in the high 16 bits
// of each exchanged dword (round-4-verified); the flag is only a cheap hint.
__device__ __forceinline__ void store_sc1_b32(void* p, unsigned int v) {
    asm volatile("global_store_dword %0, %1, off sc1" :: "v"(p), "v"(v) : "memory");
}
__device__ __forceinline__ unsigned int load_sc1_b32(const void* p) {   // waiting probe
    unsigned int v;
    asm volatile("global_load_dword %0, %1, off sc1\n"
                 "s_waitcnt vmcnt(0)"
                 : "=v"(v) : "v"(p) : "memory");
    return v;
}
__device__ __forceinline__ unsigned int load_sc1_b32_nw(const void* p) { // no-wait probe
    unsigned int v;
    asm volatile("global_load_dword %0, %1, off sc1" : "=v"(v) : "v"(p) : "memory");
    return v;
}
__device__ __forceinline__ u32x4 load_sc1_x4(const void* p) {            // no-wait bulk
    u32x4 v;
    asm volatile("global_load_dwordx4 %0, %1, off sc1" : "=v"(v) : "v"(p) : "memory");
    return v;
}

__device__ __forceinline__ unsigned short ldnt_u16(const __hip_bfloat16* p) {
    return __builtin_nontemporal_load((const unsigned short*)p);
}

// ---------------- Phase 0: zero the exchange/flag state (graph-safe) ----------------
// Zeroed exchange = tag 0 + bf16 0.0 everywhere: exactly "h_0 = 0 is ready".
__global__ __launch_bounds__(256) void init_kernel(unsigned int* __restrict__ p, int n)
{
    const int i = blockIdx.x * 256 + threadIdx.x;
    if (i < n) p[i] = 0u;
}

// ---------------- Phase 1: Xp = bf16(X @ Wih^T + (bih + bhh))  (both directions) ----------------
// X: fp32 [B*T, 512], row m = b*1024 + t.  Wih: fp32 [1024, 512] (B^T layout).
// Xp layout CHANGED this round: [t][s=16][b=64][g=4][j=16] bf16 so that a rec
// wave's per-step read is a fully-dense contiguous 2 KB window (kills the ~3x
// HBM over-fetch of the old [t][b][n] layout).
__global__ __launch_bounds__(256) void xproj_kernel(
    const float* __restrict__ X,
    const float* __restrict__ WihF,
    const float* __restrict__ bihF,
    const float* __restrict__ bhhF,
    const float* __restrict__ WihB,
    const float* __restrict__ bihB,
    const float* __restrict__ bhhB,
    __hip_bfloat16* __restrict__ XpF,
    __hip_bfloat16* __restrict__ XpB)
{
    const int dir = blockIdx.z;
    const float* W  = dir ? WihB : WihF;
    const float* bi = dir ? bihB : bihF;
    const float* bh = dir ? bhhB : bhhF;
    __hip_bfloat16* Xp = dir ? XpB : XpF;

    __shared__ __align__(16) short As[128 * 32];
    __shared__ __align__(16) short Bs[128 * 32];

    const int tid  = threadIdx.x;
    const int lane = tid & 63;
    const int w    = tid >> 6;
    const int quad = lane >> 4;
    const int l16  = lane & 15;
    const int wr   = w >> 1, wc = w & 1;      // 2x2 wave grid, 64x64 per wave

    const int m0 = blockIdx.x * 128;
    const int n0 = blockIdx.y * 128;

    const int srow = tid >> 2;                // staging row within 64-row half
    const int scg  = tid & 3;                 // 8-col group

    f32x4 acc[4][4] = {};

    for (int kk = 0; kk < 512; kk += 32) {
        const float* pa0 = X + (size_t)(m0 + srow)      * 512 + kk + scg * 8;
        const float* pa1 = X + (size_t)(m0 + 64 + srow) * 512 + kk + scg * 8;
        const float* pb0 = W + (size_t)(n0 + srow)      * 512 + kk + scg * 8;
        const float* pb1 = W + (size_t)(n0 + 64 + srow) * 512 + kk + scg * 8;
        bf8 a0 = pack_bf8(*(const float4*)pa0, *(const float4*)(pa0 + 4));
        bf8 a1 = pack_bf8(*(const float4*)pa1, *(const float4*)(pa1 + 4));
        bf8 b0 = pack_bf8(*(const float4*)pb0, *(const float4*)(pb0 + 4));
        bf8 b1 = pack_bf8(*(const float4*)pb1, *(const float4*)(pb1 + 4));
        __syncthreads();  // previous iteration's LDS reads done
        *(bf8*)&As[(srow)      * 32 + scg * 8] = a0;
        *(bf8*)&As[(64 + srow) * 32 + scg * 8] = a1;
        *(bf8*)&Bs[(srow)      * 32 + scg * 8] = b0;
        *(bf8*)&Bs[(64 + srow) * 32 + scg * 8] = b1;
        __syncthreads();

        bf8 af[4], bfr[4];
#pragma unroll
        for (int mt = 0; mt < 4; mt++)
            af[mt] = *(const bf8*)&As[(wr * 64 + mt * 16 + l16) * 32 + quad * 8];
#pragma unroll
        for (int nt = 0; nt < 4; nt++)
            bfr[nt] = *(const bf8*)&Bs[(wc * 64 + nt * 16 + l16) * 32 + quad * 8];
#pragma unroll
        for (int mt = 0; mt < 4; mt++)
#pragma unroll
            for (int nt = 0; nt < 4; nt++)
                acc[mt][nt] = __builtin_amdgcn_mfma_f32_16x16x32_bf16(af[mt], bfr[nt], acc[mt][nt], 0, 0, 0);
    }

#pragma unroll
    for (int nt = 0; nt < 4; nt++) {
        const int n = n0 + wc * 64 + nt * 16 + l16;   // n0, wc*64, nt*16 all multiples of 16 -> j == l16
        const float bias = bi[n] + bh[n];
        const int g = n >> 8, s = (n >> 4) & 15, j = n & 15;
#pragma unroll
        for (int mt = 0; mt < 4; mt++) {
#pragma unroll
            for (int r = 0; r < 4; r++) {
                const int m = m0 + wr * 64 + mt * 16 + quad * 4 + r;   // C/D: row=quad*4+r, col=l16
                const int b = m >> 10, t = m & 1023;                    // m = b*1024 + t
                Xp[((((size_t)t * 16 + s) * 64 + b) * 4 + g) * 16 + j] =
                    __float2bfloat16(acc[mt][nt][r] + bias);
            }
        }
    }
}

// ---------------- Phase 2: recurrence, drain-free tagged exchange. ----------------
// 32 WGs = 128 independent WAVES (dir, slice s, batch-tile w); no barriers, no LDS.
// Exchange EX[buf=2][dir=2][slice=16][b=64][j=16] dwords, dword = (tag<<16)|bf16(h),
// tag = step index (h_tau tagged tau). Producer wave: fire-and-forget sc1 data
// stores, then sc1 flag store (hint only, no drain — tags carry the truth).
// Consumer wave, per step: issue Xp + all 16 Af dwordx4 + flag probe together,
// ONE vmcnt(0); if flag>=tau and all 64 tags==tau -> compute (1-RT fast path).
// Else: light flag probes (16 lanes' worth of dwords, round-3 style) and a
// validated reload. Bounded -> fail-fast into verification, never a hang.
__global__ __launch_bounds__(256, 1) void lstm_rec_kernel(
    const __hip_bfloat16* __restrict__ XpF,
    const __hip_bfloat16* __restrict__ XpB,
    const float* __restrict__ WhhF,
    const float* __restrict__ WhhB,
    unsigned int* __restrict__ ex,
    unsigned int* __restrict__ flags,   // [dir=2][s=16][w=4] dwords
    float* __restrict__ out)
{
    const int wg  = blockIdx.x;
    const int dir = wg >> 4;
    const int s   = wg & 15;
    const int tid  = threadIdx.x;
    const int lane = tid & 63;
    const int w    = tid >> 6;       // wave = batch tile (16 batches)
    const int quad = lane >> 4;
    const int l16  = lane & 15;

    const __hip_bfloat16* Xp = dir ? XpB : XpF;
    const float* Whh         = dir ? WhhB : WhhF;

    // Preload Whh slice into registers: Bf[gate][kstep], B-frag layout n=l16, k=quad*8+j.
    bf8 Bf[4][8];
#pragma unroll
    for (int g = 0; g < 4; g++)
#pragma unroll
        for (int k = 0; k < 8; k++) {
            const float* p = Whh + (size_t)(g * 256 + s * 16 + l16) * 256 + k * 32 + quad * 8;
            Bf[g][k] = pack_bf8(*(const float4*)p, *(const float4*)(p + 4));
        }

    float c[4] = {0.f, 0.f, 0.f, 0.f};   // cell state, fp32, never rounded

    // Consumer A-frag addressing (round-4-verified): frag (k8): slice row
    // (k8*2 + crow), dword offset coff within slice; A layout m=l16, k=quad*8+j.
    const int crow = quad >> 1;
    const int coff = (w * 16 + l16) * 16 + (quad & 1) * 8;
    unsigned int* const exdir = ex + (dir << 14);
    unsigned int* const myflag   = flags + (dir * 16 + s) * 4 + w;        // producer
    unsigned int* const pollflag = flags + (dir * 16 + (lane & 15)) * 4 + w;  // consumer probe

    for (int tau = 0; tau < T_SEQ; tau++) {
        const int t = dir ? (T_SEQ - 1 - tau) : tau;

        // ---- combined first round: Xp + speculative Af + flag probe, one vmcnt ----
        const __hip_bfloat16* xrow = Xp + ((((size_t)t * 16 + s) * 64 + w * 16) * 4) * 16;
        unsigned short xpu[4][4];
#pragma unroll
        for (int g = 0; g < 4; g++)
#pragma unroll
            for (int r = 0; r < 4; r++)
                xpu[g][r] = ldnt_u16(&xrow[((quad * 4 + r) * 4 + g) * 16 + l16]);

        const unsigned int tagw = (unsigned int)tau << 16;
        unsigned int* const exc = exdir + ((tau & 1) << 15);
        u32x4 dd[16];
#pragma unroll
        for (int k8 = 0; k8 < 8; k8++) {
            dd[2 * k8]     = load_sc1_x4(exc + (k8 * 2 + crow) * 1024 + coff);
            dd[2 * k8 + 1] = load_sc1_x4(exc + (k8 * 2 + crow) * 1024 + coff + 4);
        }
        unsigned int fv = load_sc1_b32_nw(pollflag);
        asm volatile("s_waitcnt vmcnt(0)" ::: "memory");
        __builtin_amdgcn_sched_barrier(0);   // rule 18: keep checks below the waitcnt

        unsigned int diff = 0;
#pragma unroll
        for (int i = 0; i < 16; i++) {
            diff |= (dd[i][0] ^ tagw) & 0xFFFF0000u;
            diff |= (dd[i][1] ^ tagw) & 0xFFFF0000u;
            diff |= (dd[i][2] ^ tagw) & 0xFFFF0000u;
            diff |= (dd[i][3] ^ tagw) & 0xFFFF0000u;
        }
        bool ok = __all((int)((diff == 0u) & (fv >= (unsigned int)tau)));

        // ---- fallback: light flag probe, then validated reload ----
        int guard = 0;
        while (!ok && ++guard < (1 << 15)) {
            fv = load_sc1_b32(pollflag);                 // cheap: 16 dwords per wave
            if (!__all((int)(fv >= (unsigned int)tau))) continue;
#pragma unroll
            for (int k8 = 0; k8 < 8; k8++) {
                dd[2 * k8]     = load_sc1_x4(exc + (k8 * 2 + crow) * 1024 + coff);
                dd[2 * k8 + 1] = load_sc1_x4(exc + (k8 * 2 + crow) * 1024 + coff + 4);
            }
            asm volatile("s_waitcnt vmcnt(0)" ::: "memory");
            __builtin_amdgcn_sched_barrier(0);
            diff = 0;
#pragma unroll
            for (int i = 0; i < 16; i++) {
                diff |= (dd[i][0] ^ tagw) & 0xFFFF0000u;
                diff |= (dd[i][1] ^ tagw) & 0xFFFF0000u;
                diff |= (dd[i][2] ^ tagw) & 0xFFFF0000u;
                diff |= (dd[i][3] ^ tagw) & 0xFFFF0000u;
            }
            ok = __all((int)(diff == 0u));
        }

        // Unpack A-frags: Af[k8] = 8 bf16 from the low halves of dd[2k8], dd[2k8+1].
        bf8 Af[8];
#pragma unroll
        for (int k8 = 0; k8 < 8; k8++) {
#pragma unroll
            for (int j = 0; j < 4; j++) {
                Af[k8][j]     = (short)(dd[2 * k8][j]     & 0xFFFFu);
                Af[k8][4 + j] = (short)(dd[2 * k8 + 1][j] & 0xFFFFu);
            }
        }

        f32x4 acc[4];
        const f32x4 zero = {0.f, 0.f, 0.f, 0.f};
#pragma unroll
        for (int g = 0; g < 4; g++) acc[g] = zero;
#pragma unroll
        for (int k = 0; k < 8; k++)
#pragma unroll
            for (int g = 0; g < 4; g++)
                acc[g] = __builtin_amdgcn_mfma_f32_16x16x32_bf16(Af[k], Bf[g][k], acc[g], 0, 0, 0);

        // Gates; lane holds i,f,g,o for (b = w*16+quad*4+r, j = s*16+l16).
        // Publish h_{tau+1} per value immediately: tagged dword, fire-and-forget.
        const unsigned int pubtag = (unsigned int)(tau + 1) << 16;
        unsigned int* const dst = exdir + (((tau + 1) & 1) << 15) + (s << 10);
        float hv[4];
#pragma unroll
        for (int r = 0; r < 4; r++) {
            union { unsigned int u; float f; } cv0, cv1, cv2, cv3;
            cv0.u = (unsigned int)xpu[0][r] << 16;
            cv1.u = (unsigned int)xpu[1][r] << 16;
            cv2.u = (unsigned int)xpu[2][r] << 16;
            cv3.u = (unsigned int)xpu[3][r] << 16;
            const float ig = sigm(acc[0][r] + cv0.f);
            const float fg = sigm(acc[1][r] + cv1.f);
            const float gg = tanh_(acc[2][r] + cv2.f);
            const float og = sigm(acc[3][r] + cv3.f);
            c[r] = fg * c[r] + ig * gg;
            hv[r] = og * tanh_(c[r]);
            const int b = w * 16 + quad * 4 + r;
            store_sc1_b32(&dst[b * 16 + l16],
                          pubtag | (unsigned int)(unsigned short)bf16s(hv[r]));
        }
        // Flag hint right after data (no drain; tags carry correctness).
        if (lane == 0) store_sc1_b32(myflag, (unsigned int)(tau + 1));

        // Output stores (fp32, off the critical path; drain overlaps next poll).
#pragma unroll
        for (int r = 0; r < 4; r++) {
            const int b = w * 16 + quad * 4 + r;
            __builtin_nontemporal_store(hv[r], &out[((size_t)b * T_SEQ + t) * 512 + dir * 256 + s * 16 + l16]);
        }
    }
}

extern "C" void kernel_launch(void* const* d_in, const int* in_sizes, int n_in,
                              void* d_out, int out_size, void* d_ws, size_t ws_size,
                              hipStream_t stream)
{
    const float* X    = (const float*)d_in[0];
    const float* WihF = (const float*)d_in[1];
    const float* WhhF = (const float*)d_in[2];
    const float* bihF = (const float*)d_in[3];
    const float* bhhF = (const float*)d_in[4];
    const float* WihB = (const float*)d_in[5];
    const float* WhhB = (const float*)d_in[6];
    const float* bihB = (const float*)d_in[7];
    const float* bhhB = (const float*)d_in[8];
    float* out = (float*)d_out;

    char* ws = (char*)d_ws;
    __hip_bfloat16* XpF   = (__hip_bfloat16*)ws;                  // 128 MB
    __hip_bfloat16* XpB   = (__hip_bfloat16*)(ws + 134217728);    // 128 MB
    unsigned int*   ex    = (unsigned int*)(ws + 268435456);      // 256 KB tagged exchange
    unsigned int*   flags = (unsigned int*)(ws + 268435456 + 262144);  // 512 B

    // Zero exchange + flags each replay: tag 0 + 0.0 everywhere == "h_0 ready".
    const int initN = (262144 + 512) / 4;
    init_kernel<<<(initN + 255) / 256, 256, 0, stream>>>(ex, initN);

    dim3 g1(512, 8, 2);   // 65536/128 m-tiles, 1024/128 n-tiles, 2 directions
    xproj_kernel<<<g1, 256, 0, stream>>>(X, WihF, bihF, bhhF, WihB, bihB, bhhB, XpF, XpB);
    lstm_rec_kernel<<<32, 256, 0, stream>>>(XpF, XpB, WhhF, WhhB, ex, flags, out);
}

// Round 6
// 4919.456 us; speedup vs baseline: 1.2684x; 1.2684x over previous
//
#include <hip/hip_runtime.h>
#include <hip/hip_bf16.h>

typedef __attribute__((ext_vector_type(8))) short bf8;    // 8 bf16 (4 VGPRs)
typedef __attribute__((ext_vector_type(4))) float f32x4;  // MFMA accumulator
typedef __attribute__((ext_vector_type(4))) unsigned int u32x4;  // asm-safe 128-bit payload

#define T_SEQ 1024

__device__ __forceinline__ float sigm(float x) { return 1.f / (1.f + __expf(-x)); }
__device__ __forceinline__ float tanh_(float x) { return 2.f / (1.f + __expf(-2.f * x)) - 1.f; }

__device__ __forceinline__ short bf16s(float x) {
    union { __hip_bfloat16 h; short s; } u;
    u.h = __float2bfloat16(x);
    return u.s;
}

__device__ __forceinline__ bf8 pack_bf8(const float4 a, const float4 b) {
    bf8 r;
    r[0] = bf16s(a.x); r[1] = bf16s(a.y); r[2] = bf16s(a.z); r[3] = bf16s(a.w);
    r[4] = bf16s(b.x); r[5] = bf16s(b.y); r[6] = bf16s(b.z); r[7] = bf16s(b.w);
    return r;
}

// ---- sc1 (device-scope, LLC-coherent) access helpers -----------------------
// sc1 loads/stores bypass L1 and the non-device-coherent per-XCD L2, meeting at
// the Infinity Cache (instruction class proven cross-XCD-correct in rounds 3-5).
// Protocol: NO publish drain, NO flag, NO release/acquire — readiness is
// validated per-dword by a step tag in the high 16 bits of each exchanged dword
// (verified in rounds 4 and 5). Detection is a LIGHT probe (64 B/wave), the
// bulk data load happens exactly once per step (plus rare validated retries) —
// this is the recombination of round 3's cheap detection with round 4/5's
// drain-free tagged publish, avoiding round 4/5's heavy-poll congestion.
__device__ __forceinline__ void store_sc1_b32(void* p, unsigned int v) {
    asm volatile("global_store_dword %0, %1, off sc1" :: "v"(p), "v"(v) : "memory");
}
__device__ __forceinline__ unsigned int load_sc1_b32(const void* p) {   // waiting probe
    unsigned int v;
    asm volatile("global_load_dword %0, %1, off sc1\n"
                 "s_waitcnt vmcnt(0)"
                 : "=v"(v) : "v"(p) : "memory");
    return v;
}
__device__ __forceinline__ u32x4 load_sc1_x4(const void* p) {            // no-wait bulk
    u32x4 v;
    asm volatile("global_load_dwordx4 %0, %1, off sc1" : "=v"(v) : "v"(p) : "memory");
    return v;
}

__device__ __forceinline__ unsigned short ldnt_u16(const __hip_bfloat16* p) {
    return __builtin_nontemporal_load((const unsigned short*)p);
}

// ---------------- Phase 0: zero the exchange state (graph-safe) ----------------
// Zeroed exchange = tag 0 + bf16 0.0 everywhere: exactly "h_0 = 0 is ready".
__global__ __launch_bounds__(256) void init_kernel(unsigned int* __restrict__ p, int n)
{
    const int i = blockIdx.x * 256 + threadIdx.x;
    if (i < n) p[i] = 0u;
}

// ---------------- Phase 1: Xp = bf16(X @ Wih^T + (bih + bhh))  (both directions) ----------------
// X: fp32 [B*T, 512], row m = b*1024 + t.  Wih: fp32 [1024, 512] (B^T layout).
// Xp layout [t][s=16][b=64][g=4][j=16] bf16: a rec wave's per-step read is a
// dense contiguous window (introduced round 5, verified).
__global__ __launch_bounds__(256) void xproj_kernel(
    const float* __restrict__ X,
    const float* __restrict__ WihF,
    const float* __restrict__ bihF,
    const float* __restrict__ bhhF,
    const float* __restrict__ WihB,
    const float* __restrict__ bihB,
    const float* __restrict__ bhhB,
    __hip_bfloat16* __restrict__ XpF,
    __hip_bfloat16* __restrict__ XpB)
{
    const int dir = blockIdx.z;
    const float* W  = dir ? WihB : WihF;
    const float* bi = dir ? bihB : bihF;
    const float* bh = dir ? bhhB : bhhF;
    __hip_bfloat16* Xp = dir ? XpB : XpF;

    __shared__ __align__(16) short As[128 * 32];
    __shared__ __align__(16) short Bs[128 * 32];

    const int tid  = threadIdx.x;
    const int lane = tid & 63;
    const int w    = tid >> 6;
    const int quad = lane >> 4;
    const int l16  = lane & 15;
    const int wr   = w >> 1, wc = w & 1;      // 2x2 wave grid, 64x64 per wave

    const int m0 = blockIdx.x * 128;
    const int n0 = blockIdx.y * 128;

    const int srow = tid >> 2;                // staging row within 64-row half
    const int scg  = tid & 3;                 // 8-col group

    f32x4 acc[4][4] = {};

    for (int kk = 0; kk < 512; kk += 32) {
        const float* pa0 = X + (size_t)(m0 + srow)      * 512 + kk + scg * 8;
        const float* pa1 = X + (size_t)(m0 + 64 + srow) * 512 + kk + scg * 8;
        const float* pb0 = W + (size_t)(n0 + srow)      * 512 + kk + scg * 8;
        const float* pb1 = W + (size_t)(n0 + 64 + srow) * 512 + kk + scg * 8;
        bf8 a0 = pack_bf8(*(const float4*)pa0, *(const float4*)(pa0 + 4));
        bf8 a1 = pack_bf8(*(const float4*)pa1, *(const float4*)(pa1 + 4));
        bf8 b0 = pack_bf8(*(const float4*)pb0, *(const float4*)(pb0 + 4));
        bf8 b1 = pack_bf8(*(const float4*)pb1, *(const float4*)(pb1 + 4));
        __syncthreads();  // previous iteration's LDS reads done
        *(bf8*)&As[(srow)      * 32 + scg * 8] = a0;
        *(bf8*)&As[(64 + srow) * 32 + scg * 8] = a1;
        *(bf8*)&Bs[(srow)      * 32 + scg * 8] = b0;
        *(bf8*)&Bs[(64 + srow) * 32 + scg * 8] = b1;
        __syncthreads();

        bf8 af[4], bfr[4];
#pragma unroll
        for (int mt = 0; mt < 4; mt++)
            af[mt] = *(const bf8*)&As[(wr * 64 + mt * 16 + l16) * 32 + quad * 8];
#pragma unroll
        for (int nt = 0; nt < 4; nt++)
            bfr[nt] = *(const bf8*)&Bs[(wc * 64 + nt * 16 + l16) * 32 + quad * 8];
#pragma unroll
        for (int mt = 0; mt < 4; mt++)
#pragma unroll
            for (int nt = 0; nt < 4; nt++)
                acc[mt][nt] = __builtin_amdgcn_mfma_f32_16x16x32_bf16(af[mt], bfr[nt], acc[mt][nt], 0, 0, 0);
    }

#pragma unroll
    for (int nt = 0; nt < 4; nt++) {
        const int n = n0 + wc * 64 + nt * 16 + l16;   // j == l16 (all tile offsets are x16)
        const float bias = bi[n] + bh[n];
        const int g = n >> 8, s = (n >> 4) & 15, j = n & 15;
#pragma unroll
        for (int mt = 0; mt < 4; mt++) {
#pragma unroll
            for (int r = 0; r < 4; r++) {
                const int m = m0 + wr * 64 + mt * 16 + quad * 4 + r;   // C/D: row=quad*4+r, col=l16
                const int b = m >> 10, t = m & 1023;                    // m = b*1024 + t
                Xp[((((size_t)t * 16 + s) * 64 + b) * 4 + g) * 16 + j] =
                    __float2bfloat16(acc[mt][nt][r] + bias);
            }
        }
    }
}

// ---------------- Phase 2: recurrence, drain-free tagged exchange, light probes. ----------------
// 32 WGs = 128 independent WAVES (dir, slice s, batch-tile w); no barriers, no LDS.
// Exchange EX[buf=2][dir=2][slice=16][b=64][j=16] dwords, dword = (tag<<16)|bf16(h),
// tag = step index (h_tau tagged tau).
// Producer wave (dir,s,w): after gates, 4 tagged sc1 stores (fire-and-forget; no
// drain, no flag, no fence — round-4/5-verified protocol).
// Consumer wave (dir,s,w): LIGHT probe loop — lane L probes slice (L&15) at dword
// offset w*256+255, the LAST dword written by producer wave (dir, L&15, w), whose
// 256-dword block [w*256, w*256+256) covers everything this consumer reads. When
// all 16 tags == tau: ONE bulk load (16 x dwordx4) + tag validation (retry covers
// the rare partial-arrival race). Dependencies partition by (dir,w): a producer
// reaches step tau+1's publish (which overwrites parity tau&1 at step tau+1's
// END... i.e. h_{tau+2}) only after every (dir,w)-peer has read h_tau -> the
// buffer being read is never overwritten. Stale parity content tags tau-2 != tau.
__global__ __launch_bounds__(256, 1) void lstm_rec_kernel(
    const __hip_bfloat16* __restrict__ XpF,
    const __hip_bfloat16* __restrict__ XpB,
    const float* __restrict__ WhhF,
    const float* __restrict__ WhhB,
    unsigned int* __restrict__ ex,
    float* __restrict__ out)
{
    const int wg  = blockIdx.x;
    const int dir = wg >> 4;
    const int s   = wg & 15;
    const int tid  = threadIdx.x;
    const int lane = tid & 63;
    const int w    = tid >> 6;       // wave = batch tile (16 batches)
    const int quad = lane >> 4;
    const int l16  = lane & 15;

    const __hip_bfloat16* Xp = dir ? XpB : XpF;
    const float* Whh         = dir ? WhhB : WhhF;

    // Preload Whh slice into registers: Bf[gate][kstep], B-frag layout n=l16, k=quad*8+j.
    bf8 Bf[4][8];
#pragma unroll
    for (int g = 0; g < 4; g++)
#pragma unroll
        for (int k = 0; k < 8; k++) {
            const float* p = Whh + (size_t)(g * 256 + s * 16 + l16) * 256 + k * 32 + quad * 8;
            Bf[g][k] = pack_bf8(*(const float4*)p, *(const float4*)(p + 4));
        }

    float c[4] = {0.f, 0.f, 0.f, 0.f};   // cell state, fp32, never rounded

    // Consumer A-frag addressing (round-4/5-verified): frag k8 reads slice row
    // (k8*2 + crow) at dword offset coff; A layout m=l16, k=quad*8+j.
    const int crow = quad >> 1;
    const int coff = (w * 16 + l16) * 16 + (quad & 1) * 8;
    unsigned int* const exdir = ex + (dir << 14);

    for (int tau = 0; tau < T_SEQ; tau++) {
        const int t = dir ? (T_SEQ - 1 - tau) : tau;

        // Xp loads first; their HBM latency hides under the probe loop.
        const __hip_bfloat16* xrow = Xp + ((((size_t)t * 16 + s) * 64 + w * 16) * 4) * 16;
        unsigned short xpu[4][4];
#pragma unroll
        for (int g = 0; g < 4; g++)
#pragma unroll
            for (int r = 0; r < 4; r++)
                xpu[g][r] = ldnt_u16(&xrow[((quad * 4 + r) * 4 + g) * 16 + l16]);

        const unsigned int tagv = (unsigned int)tau;
        const unsigned int tagw = tagv << 16;
        unsigned int* const exc = exdir + ((tau & 1) << 15);

        // ---- light probe: 64 B/wave/iteration, one RT per iteration ----
        {
            const unsigned int* probep = exc + (lane & 15) * 1024 + w * 256 + 255;
            int guard = 0;
            while (true) {
                const unsigned int pv = load_sc1_b32(probep);
                if (__all((int)((pv >> 16) == tagv))) break;
                if (++guard >= 4096) break;   // fail-fast into verification, never hang
            }
        }

        // ---- bulk load + tag validation (retry covers partial-arrival races) ----
        u32x4 dd[16];
        int bguard = 0;
        while (true) {
#pragma unroll
            for (int k8 = 0; k8 < 8; k8++) {
                dd[2 * k8]     = load_sc1_x4(exc + (k8 * 2 + crow) * 1024 + coff);
                dd[2 * k8 + 1] = load_sc1_x4(exc + (k8 * 2 + crow) * 1024 + coff + 4);
            }
            asm volatile("s_waitcnt vmcnt(0)" ::: "memory");
            __builtin_amdgcn_sched_barrier(0);   // rule 18: keep checks below the waitcnt
            unsigned int diff = 0;
#pragma unroll
            for (int i = 0; i < 16; i++) {
                diff |= (dd[i][0] ^ tagw) & 0xFFFF0000u;
                diff |= (dd[i][1] ^ tagw) & 0xFFFF0000u;
                diff |= (dd[i][2] ^ tagw) & 0xFFFF0000u;
                diff |= (dd[i][3] ^ tagw) & 0xFFFF0000u;
            }
            if (__all((int)(diff == 0u))) break;
            if (++bguard >= 256) break;          // fail-fast into verification
        }

        // Unpack A-frags: Af[k8] = 8 bf16 from the low halves of dd[2k8], dd[2k8+1].
        bf8 Af[8];
#pragma unroll
        for (int k8 = 0; k8 < 8; k8++) {
#pragma unroll
            for (int j = 0; j < 4; j++) {
                Af[k8][j]     = (short)(dd[2 * k8][j]     & 0xFFFFu);
                Af[k8][4 + j] = (short)(dd[2 * k8 + 1][j] & 0xFFFFu);
            }
        }

        f32x4 acc[4];
        const f32x4 zero = {0.f, 0.f, 0.f, 0.f};
#pragma unroll
        for (int g = 0; g < 4; g++) acc[g] = zero;
#pragma unroll
        for (int k = 0; k < 8; k++)
#pragma unroll
            for (int g = 0; g < 4; g++)
                acc[g] = __builtin_amdgcn_mfma_f32_16x16x32_bf16(Af[k], Bf[g][k], acc[g], 0, 0, 0);

        // Gates; lane holds i,f,g,o for (b = w*16+quad*4+r, j = s*16+l16).
        // Publish h_{tau+1} per value immediately: tagged dword, fire-and-forget.
        const unsigned int pubtag = (unsigned int)(tau + 1) << 16;
        unsigned int* const dst = exdir + (((tau + 1) & 1) << 15) + (s << 10);
        float hv[4];
#pragma unroll
        for (int r = 0; r < 4; r++) {
            union { unsigned int u; float f; } cv0, cv1, cv2, cv3;
            cv0.u = (unsigned int)xpu[0][r] << 16;
            cv1.u = (unsigned int)xpu[1][r] << 16;
            cv2.u = (unsigned int)xpu[2][r] << 16;
            cv3.u = (unsigned int)xpu[3][r] << 16;
            const float ig = sigm(acc[0][r] + cv0.f);
            const float fg = sigm(acc[1][r] + cv1.f);
            const float gg = tanh_(acc[2][r] + cv2.f);
            const float og = sigm(acc[3][r] + cv3.f);
            c[r] = fg * c[r] + ig * gg;
            hv[r] = og * tanh_(c[r]);
            const int b = w * 16 + quad * 4 + r;
            store_sc1_b32(&dst[b * 16 + l16],
                          pubtag | (unsigned int)(unsigned short)bf16s(hv[r]));
        }

        // Output stores (fp32, off the critical path; drain overlaps next probe).
#pragma unroll
        for (int r = 0; r < 4; r++) {
            const int b = w * 16 + quad * 4 + r;
            __builtin_nontemporal_store(hv[r], &out[((size_t)b * T_SEQ + t) * 512 + dir * 256 + s * 16 + l16]);
        }
    }
}

extern "C" void kernel_launch(void* const* d_in, const int* in_sizes, int n_in,
                              void* d_out, int out_size, void* d_ws, size_t ws_size,
                              hipStream_t stream)
{
    const float* X    = (const float*)d_in[0];
    const float* WihF = (const float*)d_in[1];
    const float* WhhF = (const float*)d_in[2];
    const float* bihF = (const float*)d_in[3];
    const float* bhhF = (const float*)d_in[4];
    const float* WihB = (const float*)d_in[5];
    const float* WhhB = (const float*)d_in[6];
    const float* bihB = (const float*)d_in[7];
    const float* bhhB = (const float*)d_in[8];
    float* out = (float*)d_out;

    char* ws = (char*)d_ws;
    __hip_bfloat16* XpF = (__hip_bfloat16*)ws;                  // 128 MB
    __hip_bfloat16* XpB = (__hip_bfloat16*)(ws + 134217728);    // 128 MB
    unsigned int*   ex  = (unsigned int*)(ws + 268435456);      // 256 KB tagged exchange

    // Zero the exchange each replay: tag 0 + 0.0 everywhere == "h_0 ready".
    const int initN = 65536;   // 256 KB / 4
    init_kernel<<<initN / 256, 256, 0, stream>>>(ex, initN);

    dim3 g1(512, 8, 2);   // 65536/128 m-tiles, 1024/128 n-tiles, 2 directions
    xproj_kernel<<<g1, 256, 0, stream>>>(X, WihF, bihF, bhhF, WihB, bihB, bhhB, XpF, XpB);
    lstm_rec_kernel<<<32, 256, 0, stream>>>(XpF, XpB, WhhF, WhhB, ex, out);
}